// Round 8
// baseline (1009.395 us; speedup 1.0000x reference)
//
#include <hip/hip_runtime.h>
#include <hip/hip_bf16.h>

typedef __hip_bfloat16 bf16;
typedef short v8s __attribute__((ext_vector_type(8)));      // 8 bf16 (4 VGPRs)
typedef float f32x16 __attribute__((ext_vector_type(16)));  // 32x32 MFMA acc

#define B_  32
#define L_  144
#define D_  96
#define HW_ 64

#define PIXSTRIDE 80             // 32 l * 2B = 64B data + 16B pad (bank spread)
#define WPACK_ELEMS (83*5*2*3*64*8)   // == 83*5*96*32, 2.55MB bf16

__device__ __forceinline__ unsigned short f2bf(float f) {
    union { float f; unsigned int u; } x{f};
    unsigned int r = x.u + 0x7fffu + ((x.u >> 16) & 1u);   // RNE
    return (unsigned short)(r >> 16);
}
__device__ __forceinline__ float bf2f(unsigned short u) {
    union { unsigned int u; float f; } x{(unsigned int)u << 16};
    return x.f;
}

// ---------------------------------------------------------------------------
// Weight prep for 32x32x16 A-fragments.
// Layout: wpack[(((T*5+q)*2+s)*3+dt)*512 + lane*8 + j] =
//   W[d = dt*32 + (lane&31)][k = q*32 + s*16 + (lane>>5)*8 + j]
// T: 0..48=7x7, 49..73=5x5, 74..82=3x3; k (channel) zero-padded past 143.
// ---------------------------------------------------------------------------
__global__ __launch_bounds__(256) void prep_weights(
    const float* __restrict__ w1, const float* __restrict__ w2,
    const float* __restrict__ w3, unsigned short* __restrict__ wpack)
{
    int i = blockIdx.x * 256 + threadIdx.x;
    if (i >= WPACK_ELEMS) return;
    int rest = i;
    const int j  = rest & 7;   rest >>= 3;
    const int l  = rest & 63;  rest >>= 6;
    const int dt = rest % 3;   rest /= 3;
    const int s  = rest & 1;   rest >>= 1;
    const int q  = rest % 5;
    const int T  = rest / 5;
    const int d  = dt * 32 + (l & 31);
    const int k  = q * 32 + s * 16 + (l >> 5) * 8 + j;
    float v = 0.f;
    if (k < L_) {
        if (T < 49)      v = w3[(d * L_ + k) * 49 + T];
        else if (T < 74) v = w2[(d * L_ + k) * 25 + (T - 49)];
        else             v = w1[(d * L_ + k) * 9  + (T - 74)];
    }
    wpack[i] = f2bf(v);
}

// ---------------------------------------------------------------------------
// Single-branch conv via mfma_f32_32x32x16_bf16.
// Block: 96 d x (16x16 px), 256 threads = 4 waves; wave = 3 d-tiles(32d) x
// 2 px-tiles(32px = 2 rows x 16) = 6 f32x16 accs (96 acc regs).
// Per tap: 4 B ds_read_b128 + 6 A global 16B loads + 12 MFMAs
//   -> 98 KFLOP per LDS-KB (2x the 16x16 structure).
// MODE 0: y -> slot upper half (7x7/y3); MODE 1: y -> lower (5x5/y2);
// MODE 2: y1 + combine: add -> lower, max -> upper.
// ---------------------------------------------------------------------------
template<int KSZ, int TBASE, int MODE>
__global__ __launch_bounds__(256, 3) void conv_branch(
    const float* __restrict__ x, const unsigned short* __restrict__ wpack,
    const float* __restrict__ bb, const float* __restrict__ gg,
    const float* __restrict__ bbe, const float* __restrict__ mm,
    const float* __restrict__ vv,
    float* __restrict__ outp)
{
    constexpr int PAD  = KSZ / 2;
    constexpr int PXR  = 16 + 2 * PAD;    // patch rows/cols
    constexpr int NPIX = PXR * PXR;
    constexpr int NP   = NPIX * 32;       // staged elements per l-chunk

    __shared__ __align__(16) unsigned char patchB[NPIX * PIXSTRIDE];
    __shared__ float bns[96 * 2];

    const int t    = threadIdx.x;
    const int lane = t & 63;
    const int wid  = t >> 6;           // 0..3 : wave -> 4 px rows
    const int lo32 = lane & 31;        // A: d-in-tile / B,C: px-in-tile
    const int hi2  = lane >> 5;        // k-group (0..1)
    const int rbase = wid * 4;         // wave's first px row

    const int st = blockIdx.x;
    const int h0 = (st >> 2) << 4;
    const int w0 = (st & 3) << 4;
    const int b  = blockIdx.y;

    // B byte offset for pt=0, s=0, tap(0,0): pixel p=lo32 -> row rbase+(p>>4), col p&15
    const int laneB0 = ((rbase + (lo32 >> 4)) * PXR + (lo32 & 15)) * PIXSTRIDE + hi2 * 16;
    const int laneA  = lane * 8;       // elems into each 512-elem A block

    if (t < 96) {
        const float iv = gg[t] * rsqrtf(vv[t] + 1e-5f);
        bns[t*2+0] = iv;
        bns[t*2+1] = fmaf(bb[t] - mm[t], iv, bbe[t]);
    }

    f32x16 acc[3][2];
    #pragma unroll
    for (int dt = 0; dt < 3; ++dt)
        #pragma unroll
        for (int pt = 0; pt < 2; ++pt) acc[dt][pt] = (f32x16)0.f;

    const unsigned short* wBase = wpack + laneA;   // + T*15360 + q*3072 + s*1536 + dt*512

    for (int q = 0; q < 5; ++q) {
        __syncthreads();
        // ---- stage patch chunk q: [pixel][32 ch] bf16, 80B pixel stride ----
        for (int i = t; i < NP; i += 256) {
            const int l   = i / NPIX;
            const int pix = i - l * NPIX;
            const int r = pix / PXR, c = pix - r * PXR;
            const int gh = h0 - PAD + r, gw = w0 - PAD + c;
            const int lg = q * 32 + l;
            float v = 0.f;
            if (lg < L_ && (unsigned)gh < 64u && (unsigned)gw < 64u)
                v = x[(((size_t)b * L_ + lg) << 12) + (gh << 6) + gw];
            *(unsigned short*)(patchB + pix * PIXSTRIDE + l * 2) = f2bf(v);
        }
        __syncthreads();

        const unsigned short* wqc = wBase + q * 3072;

        for (int kh = 0; kh < KSZ; ++kh) {
            #pragma unroll
            for (int kw = 0; kw < KSZ; ++kw) {
                const int tapB = laneB0 + (kh * PXR + kw) * PIXSTRIDE;
                const unsigned short* wp = wqc + (TBASE + kh * KSZ + kw) * 15360;

                // ---- k-half s=0 ----
                {
                    const v8s B0 = *(const v8s*)(patchB + tapB);
                    const v8s B1 = *(const v8s*)(patchB + tapB + 2 * PXR * PIXSTRIDE);
                    const v8s A0 = *(const v8s*)(wp);
                    const v8s A1 = *(const v8s*)(wp + 512);
                    const v8s A2 = *(const v8s*)(wp + 1024);
                    acc[0][0] = __builtin_amdgcn_mfma_f32_32x32x16_bf16(A0, B0, acc[0][0], 0, 0, 0);
                    acc[0][1] = __builtin_amdgcn_mfma_f32_32x32x16_bf16(A0, B1, acc[0][1], 0, 0, 0);
                    acc[1][0] = __builtin_amdgcn_mfma_f32_32x32x16_bf16(A1, B0, acc[1][0], 0, 0, 0);
                    acc[1][1] = __builtin_amdgcn_mfma_f32_32x32x16_bf16(A1, B1, acc[1][1], 0, 0, 0);
                    acc[2][0] = __builtin_amdgcn_mfma_f32_32x32x16_bf16(A2, B0, acc[2][0], 0, 0, 0);
                    acc[2][1] = __builtin_amdgcn_mfma_f32_32x32x16_bf16(A2, B1, acc[2][1], 0, 0, 0);
                }
                // ---- k-half s=1 ----
                {
                    const v8s B0 = *(const v8s*)(patchB + tapB + 32);
                    const v8s B1 = *(const v8s*)(patchB + tapB + 2 * PXR * PIXSTRIDE + 32);
                    const v8s A0 = *(const v8s*)(wp + 1536);
                    const v8s A1 = *(const v8s*)(wp + 1536 + 512);
                    const v8s A2 = *(const v8s*)(wp + 1536 + 1024);
                    acc[0][0] = __builtin_amdgcn_mfma_f32_32x32x16_bf16(A0, B0, acc[0][0], 0, 0, 0);
                    acc[0][1] = __builtin_amdgcn_mfma_f32_32x32x16_bf16(A0, B1, acc[0][1], 0, 0, 0);
                    acc[1][0] = __builtin_amdgcn_mfma_f32_32x32x16_bf16(A1, B0, acc[1][0], 0, 0, 0);
                    acc[1][1] = __builtin_amdgcn_mfma_f32_32x32x16_bf16(A1, B1, acc[1][1], 0, 0, 0);
                    acc[2][0] = __builtin_amdgcn_mfma_f32_32x32x16_bf16(A2, B0, acc[2][0], 0, 0, 0);
                    acc[2][1] = __builtin_amdgcn_mfma_f32_32x32x16_bf16(A2, B1, acc[2][1], 0, 0, 0);
                }
            }
        }
    }

    // ---- epilogue ----
    // C/D (verified m74/m101): col = lane&31 (px), row = (reg&3)+8*(reg>>2)+4*(lane>>5)
    #pragma unroll
    for (int dt = 0; dt < 3; ++dt) {
        #pragma unroll
        for (int pt = 0; pt < 2; ++pt) {
            #pragma unroll
            for (int reg = 0; reg < 16; ++reg) {
                const int row = (reg & 3) + 8 * (reg >> 2) + 4 * hi2;
                const int d = dt * 32 + row;
                const float iv = bns[d*2+0], cv = bns[d*2+1];
                unsigned short* pl = (unsigned short*)(outp + (((size_t)b * D_ + d) << 12));
                const int h = h0 + rbase + pt * 2 + (lo32 >> 4);
                const int idx = (h << 6) + w0 + (lo32 & 15);
                const float y = fmaxf(0.f, fmaf(acc[dt][pt][reg], iv, cv));
                if constexpr (MODE == 0) {
                    pl[4096 + idx] = f2bf(y);
                } else if constexpr (MODE == 1) {
                    pl[idx] = f2bf(y);
                } else {
                    const float y2 = bf2f(pl[idx]);
                    const float y3 = bf2f(pl[4096 + idx]);
                    const float av = y + y2 + y3;
                    const float mv = fmaxf(y, fmaxf(y2, y3));
                    pl[idx]        = f2bf(av);
                    pl[4096 + idx] = f2bf(mv);
                }
            }
        }
    }
}

// ---------------------------------------------------------------------------
// Kernel B: per-plane 3x3 conv over [add; max] with avg folded (unchanged).
// ---------------------------------------------------------------------------
__global__ __launch_bounds__(256) void fuse_kernel(
    const float* __restrict__ wf, float* __restrict__ out)
{
    const int p = blockIdx.x;      // plane = b*96 + d
    const int t = threadIdx.x;
    __shared__ float sa[66 * 66];
    __shared__ float sm[66 * 66];
    const bf16* base = (const bf16*)(out + ((size_t)p << 12));

    for (int i = t; i < 66 * 66; i += 256) {
        const int c = i % 66, r = i / 66;
        const int gh = r - 1, gw = c - 1;
        float va = 0.f, vm = 0.f;
        if (gh >= 0 && gh < 64 && gw >= 0 && gw < 64) {
            va = __bfloat162float(base[(gh << 6) + gw]);
            vm = __bfloat162float(base[4096 + (gh << 6) + gw]);
        }
        sa[i] = va; sm[i] = vm;
    }

    float wa[9], wm[9];
    #pragma unroll
    for (int j = 0; j < 9; ++j) {
        wa[j] = wf[j] + wf[9 + j] * (1.f / 3.f);
        wm[j] = wf[18 + j];
    }
    __syncthreads();

    float* op = out + ((size_t)p << 12);
    for (int i = t; i < 4096; i += 256) {
        const int h = i >> 6, w = i & 63;
        float acc = 0.f;
        #pragma unroll
        for (int kh = 0; kh < 3; ++kh) {
            #pragma unroll
            for (int kw = 0; kw < 3; ++kw) {
                acc = fmaf(sa[(h + kh) * 66 + (w + kw)], wa[kh * 3 + kw], acc);
                acc = fmaf(sm[(h + kh) * 66 + (w + kw)], wm[kh * 3 + kw], acc);
            }
        }
        op[i] = acc;
    }
}

extern "C" void kernel_launch(void* const* d_in, const int* in_sizes, int n_in,
                              void* d_out, int out_size, void* d_ws, size_t ws_size,
                              hipStream_t stream)
{
    const float* x   = (const float*)d_in[0];
    const float* w1  = (const float*)d_in[1];
    const float* b1  = (const float*)d_in[2];
    const float* g1  = (const float*)d_in[3];
    const float* be1 = (const float*)d_in[4];
    const float* m1  = (const float*)d_in[5];
    const float* v1  = (const float*)d_in[6];
    const float* w2  = (const float*)d_in[7];
    const float* b2  = (const float*)d_in[8];
    const float* g2  = (const float*)d_in[9];
    const float* be2 = (const float*)d_in[10];
    const float* m2  = (const float*)d_in[11];
    const float* v2  = (const float*)d_in[12];
    const float* w3  = (const float*)d_in[13];
    const float* b3  = (const float*)d_in[14];
    const float* g3  = (const float*)d_in[15];
    const float* be3 = (const float*)d_in[16];
    const float* m3  = (const float*)d_in[17];
    const float* v3  = (const float*)d_in[18];
    const float* wf  = (const float*)d_in[19];
    float* out = (float*)d_out;

    // d_ws: packed bf16 weights only (2.55 MB, proven safe rounds 4-7)
    unsigned short* wpack = (unsigned short*)d_ws;

    prep_weights<<<(WPACK_ELEMS + 255) / 256, 256, 0, stream>>>(w1, w2, w3, wpack);

    dim3 gridA(16, B_);   // 16 spatial tiles x 32 batch
    conv_branch<7, 0, 0><<<gridA, 256, 0, stream>>>(x, wpack, b3, g3, be3, m3, v3, out);
    conv_branch<5, 49, 1><<<gridA, 256, 0, stream>>>(x, wpack, b2, g2, be2, m2, v2, out);
    conv_branch<3, 74, 2><<<gridA, 256, 0, stream>>>(x, wpack, b1, g1, be1, m1, v1, out);

    fuse_kernel<<<B_ * D_, 256, 0, stream>>>(wf, out);
}

// Round 9
// 885.525 us; speedup vs baseline: 1.1399x; 1.1399x over previous
//
#include <hip/hip_runtime.h>
#include <hip/hip_bf16.h>

typedef __hip_bfloat16 bf16;
typedef short v8s __attribute__((ext_vector_type(8)));      // 8 bf16 (4 VGPRs)
typedef float f32x16 __attribute__((ext_vector_type(16)));  // 32x32 MFMA acc

#define B_  32
#define L_  144
#define D_  96
#define HW_ 64

#define PIXSTRIDE 80             // 32 l * 2B = 64B data + 16B pad (bank spread)
#define WPACK_ELEMS (83*5*2*3*64*8)   // == 83*5*96*32, 2.55MB bf16

__device__ __forceinline__ unsigned short f2bf(float f) {
    union { float f; unsigned int u; } x{f};
    unsigned int r = x.u + 0x7fffu + ((x.u >> 16) & 1u);   // RNE
    return (unsigned short)(r >> 16);
}
__device__ __forceinline__ float bf2f(unsigned short u) {
    union { unsigned int u; float f; } x{(unsigned int)u << 16};
    return x.f;
}

// ---------------------------------------------------------------------------
// Weight prep for 32x32x16 A-fragments.
// Layout: wpack[(((T*5+q)*2+s)*3+dt)*512 + lane*8 + j] =
//   W[d = dt*32 + (lane&31)][k = q*32 + s*16 + (lane>>5)*8 + j]
// T: 0..48=7x7, 49..73=5x5, 74..82=3x3; k (channel) zero-padded past 143.
// ---------------------------------------------------------------------------
__global__ __launch_bounds__(256) void prep_weights(
    const float* __restrict__ w1, const float* __restrict__ w2,
    const float* __restrict__ w3, unsigned short* __restrict__ wpack)
{
    int i = blockIdx.x * 256 + threadIdx.x;
    if (i >= WPACK_ELEMS) return;
    int rest = i;
    const int j  = rest & 7;   rest >>= 3;
    const int l  = rest & 63;  rest >>= 6;
    const int dt = rest % 3;   rest /= 3;
    const int s  = rest & 1;   rest >>= 1;
    const int q  = rest % 5;
    const int T  = rest / 5;
    const int d  = dt * 32 + (l & 31);
    const int k  = q * 32 + s * 16 + (l >> 5) * 8 + j;
    float v = 0.f;
    if (k < L_) {
        if (T < 49)      v = w3[(d * L_ + k) * 49 + T];
        else if (T < 74) v = w2[(d * L_ + k) * 25 + (T - 49)];
        else             v = w1[(d * L_ + k) * 9  + (T - 74)];
    }
    wpack[i] = f2bf(v);
}

// ---------------------------------------------------------------------------
// Single-branch conv via mfma_f32_32x32x16_bf16.
// Block: 96 d x (16x16 px), 256 threads = 4 waves; wave = 3 d-tiles(32d) x
// 2 px-tiles(32px = 2 rows x 16) = 6 f32x16 accs (96 acc regs).
// __launch_bounds__(256, 2): 256-reg budget so the 96 acc regs stay in the
// unified RF — (256,3)'s 170-reg cap spilled accs to scratch (round 8:
// 630 MB scratch traffic, 2x slowdown).
// MODE 0: y -> slot upper half (7x7/y3); MODE 1: y -> lower (5x5/y2);
// MODE 2: y1 + combine: add -> lower, max -> upper.
// ---------------------------------------------------------------------------
template<int KSZ, int TBASE, int MODE>
__global__ __launch_bounds__(256, 2) void conv_branch(
    const float* __restrict__ x, const unsigned short* __restrict__ wpack,
    const float* __restrict__ bb, const float* __restrict__ gg,
    const float* __restrict__ bbe, const float* __restrict__ mm,
    const float* __restrict__ vv,
    float* __restrict__ outp)
{
    constexpr int PAD  = KSZ / 2;
    constexpr int PXR  = 16 + 2 * PAD;    // patch rows/cols
    constexpr int NPIX = PXR * PXR;
    constexpr int NP   = NPIX * 32;       // staged elements per l-chunk

    __shared__ __align__(16) unsigned char patchB[NPIX * PIXSTRIDE];
    __shared__ float bns[96 * 2];

    const int t    = threadIdx.x;
    const int lane = t & 63;
    const int wid  = t >> 6;           // 0..3 : wave -> 4 px rows
    const int lo32 = lane & 31;        // A: d-in-tile / B,C: px-in-tile
    const int hi2  = lane >> 5;        // k-group (0..1)
    const int rbase = wid * 4;         // wave's first px row

    const int st = blockIdx.x;
    const int h0 = (st >> 2) << 4;
    const int w0 = (st & 3) << 4;
    const int b  = blockIdx.y;

    // B byte offset for pt=0, s=0, tap(0,0): pixel p=lo32 -> row rbase+(p>>4), col p&15
    const int laneB0 = ((rbase + (lo32 >> 4)) * PXR + (lo32 & 15)) * PIXSTRIDE + hi2 * 16;
    const int laneA  = lane * 8;       // elems into each 512-elem A block

    if (t < 96) {
        const float iv = gg[t] * rsqrtf(vv[t] + 1e-5f);
        bns[t*2+0] = iv;
        bns[t*2+1] = fmaf(bb[t] - mm[t], iv, bbe[t]);
    }

    f32x16 acc[3][2];
    #pragma unroll
    for (int dt = 0; dt < 3; ++dt)
        #pragma unroll
        for (int pt = 0; pt < 2; ++pt) acc[dt][pt] = (f32x16)0.f;

    const unsigned short* wBase = wpack + laneA;   // + T*15360 + q*3072 + s*1536 + dt*512

    for (int q = 0; q < 5; ++q) {
        __syncthreads();
        // ---- stage patch chunk q: [pixel][32 ch] bf16, 80B pixel stride ----
        for (int i = t; i < NP; i += 256) {
            const int l   = i / NPIX;
            const int pix = i - l * NPIX;
            const int r = pix / PXR, c = pix - r * PXR;
            const int gh = h0 - PAD + r, gw = w0 - PAD + c;
            const int lg = q * 32 + l;
            float v = 0.f;
            if (lg < L_ && (unsigned)gh < 64u && (unsigned)gw < 64u)
                v = x[(((size_t)b * L_ + lg) << 12) + (gh << 6) + gw];
            *(unsigned short*)(patchB + pix * PIXSTRIDE + l * 2) = f2bf(v);
        }
        __syncthreads();

        const unsigned short* wqc = wBase + q * 3072;

        for (int kh = 0; kh < KSZ; ++kh) {
            #pragma unroll
            for (int kw = 0; kw < KSZ; ++kw) {
                const int tapB = laneB0 + (kh * PXR + kw) * PIXSTRIDE;
                const unsigned short* wp = wqc + (TBASE + kh * KSZ + kw) * 15360;

                // ---- k-half s=0 ----
                {
                    const v8s B0 = *(const v8s*)(patchB + tapB);
                    const v8s B1 = *(const v8s*)(patchB + tapB + 2 * PXR * PIXSTRIDE);
                    const v8s A0 = *(const v8s*)(wp);
                    const v8s A1 = *(const v8s*)(wp + 512);
                    const v8s A2 = *(const v8s*)(wp + 1024);
                    acc[0][0] = __builtin_amdgcn_mfma_f32_32x32x16_bf16(A0, B0, acc[0][0], 0, 0, 0);
                    acc[0][1] = __builtin_amdgcn_mfma_f32_32x32x16_bf16(A0, B1, acc[0][1], 0, 0, 0);
                    acc[1][0] = __builtin_amdgcn_mfma_f32_32x32x16_bf16(A1, B0, acc[1][0], 0, 0, 0);
                    acc[1][1] = __builtin_amdgcn_mfma_f32_32x32x16_bf16(A1, B1, acc[1][1], 0, 0, 0);
                    acc[2][0] = __builtin_amdgcn_mfma_f32_32x32x16_bf16(A2, B0, acc[2][0], 0, 0, 0);
                    acc[2][1] = __builtin_amdgcn_mfma_f32_32x32x16_bf16(A2, B1, acc[2][1], 0, 0, 0);
                }
                // ---- k-half s=1 ----
                {
                    const v8s B0 = *(const v8s*)(patchB + tapB + 32);
                    const v8s B1 = *(const v8s*)(patchB + tapB + 2 * PXR * PIXSTRIDE + 32);
                    const v8s A0 = *(const v8s*)(wp + 1536);
                    const v8s A1 = *(const v8s*)(wp + 1536 + 512);
                    const v8s A2 = *(const v8s*)(wp + 1536 + 1024);
                    acc[0][0] = __builtin_amdgcn_mfma_f32_32x32x16_bf16(A0, B0, acc[0][0], 0, 0, 0);
                    acc[0][1] = __builtin_amdgcn_mfma_f32_32x32x16_bf16(A0, B1, acc[0][1], 0, 0, 0);
                    acc[1][0] = __builtin_amdgcn_mfma_f32_32x32x16_bf16(A1, B0, acc[1][0], 0, 0, 0);
                    acc[1][1] = __builtin_amdgcn_mfma_f32_32x32x16_bf16(A1, B1, acc[1][1], 0, 0, 0);
                    acc[2][0] = __builtin_amdgcn_mfma_f32_32x32x16_bf16(A2, B0, acc[2][0], 0, 0, 0);
                    acc[2][1] = __builtin_amdgcn_mfma_f32_32x32x16_bf16(A2, B1, acc[2][1], 0, 0, 0);
                }
            }
        }
    }

    // ---- epilogue ----
    // C/D (verified m74/m101): col = lane&31 (px), row = (reg&3)+8*(reg>>2)+4*(lane>>5)
    #pragma unroll
    for (int dt = 0; dt < 3; ++dt) {
        #pragma unroll
        for (int pt = 0; pt < 2; ++pt) {
            #pragma unroll
            for (int reg = 0; reg < 16; ++reg) {
                const int row = (reg & 3) + 8 * (reg >> 2) + 4 * hi2;
                const int d = dt * 32 + row;
                const float iv = bns[d*2+0], cv = bns[d*2+1];
                unsigned short* pl = (unsigned short*)(outp + (((size_t)b * D_ + d) << 12));
                const int h = h0 + rbase + pt * 2 + (lo32 >> 4);
                const int idx = (h << 6) + w0 + (lo32 & 15);
                const float y = fmaxf(0.f, fmaf(acc[dt][pt][reg], iv, cv));
                if constexpr (MODE == 0) {
                    pl[4096 + idx] = f2bf(y);
                } else if constexpr (MODE == 1) {
                    pl[idx] = f2bf(y);
                } else {
                    const float y2 = bf2f(pl[idx]);
                    const float y3 = bf2f(pl[4096 + idx]);
                    const float av = y + y2 + y3;
                    const float mv = fmaxf(y, fmaxf(y2, y3));
                    pl[idx]        = f2bf(av);
                    pl[4096 + idx] = f2bf(mv);
                }
            }
        }
    }
}

// ---------------------------------------------------------------------------
// Kernel B: per-plane 3x3 conv over [add; max] with avg folded (unchanged).
// ---------------------------------------------------------------------------
__global__ __launch_bounds__(256) void fuse_kernel(
    const float* __restrict__ wf, float* __restrict__ out)
{
    const int p = blockIdx.x;      // plane = b*96 + d
    const int t = threadIdx.x;
    __shared__ float sa[66 * 66];
    __shared__ float sm[66 * 66];
    const bf16* base = (const bf16*)(out + ((size_t)p << 12));

    for (int i = t; i < 66 * 66; i += 256) {
        const int c = i % 66, r = i / 66;
        const int gh = r - 1, gw = c - 1;
        float va = 0.f, vm = 0.f;
        if (gh >= 0 && gh < 64 && gw >= 0 && gw < 64) {
            va = __bfloat162float(base[(gh << 6) + gw]);
            vm = __bfloat162float(base[4096 + (gh << 6) + gw]);
        }
        sa[i] = va; sm[i] = vm;
    }

    float wa[9], wm[9];
    #pragma unroll
    for (int j = 0; j < 9; ++j) {
        wa[j] = wf[j] + wf[9 + j] * (1.f / 3.f);
        wm[j] = wf[18 + j];
    }
    __syncthreads();

    float* op = out + ((size_t)p << 12);
    for (int i = t; i < 4096; i += 256) {
        const int h = i >> 6, w = i & 63;
        float acc = 0.f;
        #pragma unroll
        for (int kh = 0; kh < 3; ++kh) {
            #pragma unroll
            for (int kw = 0; kw < 3; ++kw) {
                acc = fmaf(sa[(h + kh) * 66 + (w + kw)], wa[kh * 3 + kw], acc);
                acc = fmaf(sm[(h + kh) * 66 + (w + kw)], wm[kh * 3 + kw], acc);
            }
        }
        op[i] = acc;
    }
}

extern "C" void kernel_launch(void* const* d_in, const int* in_sizes, int n_in,
                              void* d_out, int out_size, void* d_ws, size_t ws_size,
                              hipStream_t stream)
{
    const float* x   = (const float*)d_in[0];
    const float* w1  = (const float*)d_in[1];
    const float* b1  = (const float*)d_in[2];
    const float* g1  = (const float*)d_in[3];
    const float* be1 = (const float*)d_in[4];
    const float* m1  = (const float*)d_in[5];
    const float* v1  = (const float*)d_in[6];
    const float* w2  = (const float*)d_in[7];
    const float* b2  = (const float*)d_in[8];
    const float* g2  = (const float*)d_in[9];
    const float* be2 = (const float*)d_in[10];
    const float* m2  = (const float*)d_in[11];
    const float* v2  = (const float*)d_in[12];
    const float* w3  = (const float*)d_in[13];
    const float* b3  = (const float*)d_in[14];
    const float* g3  = (const float*)d_in[15];
    const float* be3 = (const float*)d_in[16];
    const float* m3  = (const float*)d_in[17];
    const float* v3  = (const float*)d_in[18];
    const float* wf  = (const float*)d_in[19];
    float* out = (float*)d_out;

    // d_ws: packed bf16 weights only (2.55 MB, proven safe rounds 4-8)
    unsigned short* wpack = (unsigned short*)d_ws;

    prep_weights<<<(WPACK_ELEMS + 255) / 256, 256, 0, stream>>>(w1, w2, w3, wpack);

    dim3 gridA(16, B_);   // 16 spatial tiles x 32 batch
    conv_branch<7, 0, 0><<<gridA, 256, 0, stream>>>(x, wpack, b3, g3, be3, m3, v3, out);
    conv_branch<5, 49, 1><<<gridA, 256, 0, stream>>>(x, wpack, b2, g2, be2, m2, v2, out);
    conv_branch<3, 74, 2><<<gridA, 256, 0, stream>>>(x, wpack, b1, g1, be1, m1, v1, out);

    fuse_kernel<<<B_ * D_, 256, 0, stream>>>(wf, out);
}

// Round 10
// 677.909 us; speedup vs baseline: 1.4890x; 1.3063x over previous
//
#include <hip/hip_runtime.h>
#include <hip/hip_bf16.h>

typedef __hip_bfloat16 bf16;
typedef short v8s __attribute__((ext_vector_type(8)));     // 8 bf16 (4 VGPRs)
typedef float f32x4 __attribute__((ext_vector_type(4)));   // MFMA acc

#define B_  32
#define L_  144
#define D_  96
#define HW_ 64

#define PIXSTRIDE 80             // 32 l * 2B = 64B data + 16B pad (bank spread)
#define WPACK_ELEMS (83*5*96*32) // packed bf16 weights

__device__ __forceinline__ unsigned short f2bf(float f) {
    union { float f; unsigned int u; } x{f};
    unsigned int r = x.u + 0x7fffu + ((x.u >> 16) & 1u);   // RNE
    return (unsigned short)(r >> 16);
}
__device__ __forceinline__ float bf2f(unsigned short u) {
    union { unsigned int u; float f; } x{(unsigned int)u << 16};
    return x.f;
}

// ---------------------------------------------------------------------------
// Weight prep: pack w1/w2/w3 (fp32, [D][L][k][k]) into A-fragment order bf16:
// wpack[((T*5+q)*96 + d)*32 + l~],  T: 0..48=7x7 taps, 49..73=5x5, 74..82=3x3,
// q = l-chunk (l = q*32+l~, zero-padded past 143).
// ---------------------------------------------------------------------------
__global__ __launch_bounds__(256) void prep_weights(
    const float* __restrict__ w1, const float* __restrict__ w2,
    const float* __restrict__ w3, unsigned short* __restrict__ wpack)
{
    int i = blockIdx.x * 256 + threadIdx.x;
    if (i >= WPACK_ELEMS) return;
    const int lt = i & 31;
    const int d  = (i >> 5) % 96;
    const int r  = (i >> 5) / 96;   // T*5 + q
    const int q  = r % 5;
    const int T  = r / 5;
    const int l  = q * 32 + lt;
    float v = 0.f;
    if (l < L_) {
        if (T < 49)      v = w3[(d * L_ + l) * 49 + T];
        else if (T < 74) v = w2[(d * L_ + l) * 25 + (T - 49)];
        else             v = w1[(d * L_ + l) * 9  + (T - 74)];
    }
    wpack[i] = f2bf(v);
}

// ---------------------------------------------------------------------------
// Single-branch MFMA conv (round-7 proven structure) + explicit 1-tap-ahead
// A-fragment register prefetch. Block: 96 d x (16x16 px), 8 waves = 2 d-halves
// x 4 px-quads; wave = 3 d-tiles x 4 px-rows = 12 accs.
// The tap loop is fully unrolled with TWO named A-sets rotated statically, so
// tap tt+1's 3 global A-loads (L2/L3, ~200-900 cy) issue before tap tt's 12
// MFMAs — the compiler does not do this on its own (round 7: VGPR 52 of a
// 128 budget, latency-bound at ~8% true MFMA-issue occupancy).
// MODE 0: y -> slot upper half (7x7/y3); MODE 1: y -> lower (5x5/y2);
// MODE 2: y1 + combine: add -> lower, max -> upper.
// ---------------------------------------------------------------------------
template<int KSZ, int TBASE, int MODE>
__global__ __launch_bounds__(512, 4) void conv_branch(
    const float* __restrict__ x, const unsigned short* __restrict__ wpack,
    const float* __restrict__ bb, const float* __restrict__ gg,
    const float* __restrict__ bbe, const float* __restrict__ mm,
    const float* __restrict__ vv,
    float* __restrict__ outp)
{
    constexpr int PAD  = KSZ / 2;
    constexpr int PXR  = 16 + 2 * PAD;    // patch rows/cols
    constexpr int NPIX = PXR * PXR;
    constexpr int NP   = NPIX * 32;       // staged elements per l-chunk
    constexpr int NT   = KSZ * KSZ;       // taps

    __shared__ __align__(16) unsigned char patchB[NPIX * PIXSTRIDE];
    __shared__ float bns[96 * 2];

    const int t    = threadIdx.x;
    const int lane = t & 63;
    const int wid  = t >> 6;           // 0..7
    const int dhalf = wid >> 2;        // 0..1
    const int ptb   = (wid & 3) * 4;   // px-quad base row
    const int lo = lane & 15;
    const int hi = lane >> 4;

    const int st = blockIdx.x;
    const int h0 = (st >> 2) << 4;
    const int w0 = (st & 3) << 4;
    const int b  = blockIdx.y;

    const int laneBoff = lo * PIXSTRIDE + hi * 16;
    const int laneAoff = lo * 32 + hi * 8;

    if (t < 96) {
        const float iv = gg[t] * rsqrtf(vv[t] + 1e-5f);
        bns[t*2+0] = iv;
        bns[t*2+1] = fmaf(bb[t] - mm[t], iv, bbe[t]);
    }

    f32x4 acc[3][4];
    #pragma unroll
    for (int dt = 0; dt < 3; ++dt)
        #pragma unroll
        for (int pp = 0; pp < 4; ++pp) acc[dt][pp] = (f32x4)0.f;

    const unsigned short* wqBase = wpack + dhalf * 1536 + laneAoff;

    for (int q = 0; q < 5; ++q) {
        __syncthreads();
        // ---- stage patch chunk q: [pixel][32 l] bf16 ----
        for (int i = t; i < NP; i += 512) {
            const int l   = i / NPIX;
            const int pix = i - l * NPIX;
            const int r = pix / PXR, c = pix - r * PXR;
            const int gh = h0 - PAD + r, gw = w0 - PAD + c;
            const int lg = q * 32 + l;
            float v = 0.f;
            if (lg < L_ && (unsigned)gh < 64u && (unsigned)gw < 64u)
                v = x[(((size_t)b * L_ + lg) << 12) + (gh << 6) + gw];
            *(unsigned short*)(patchB + pix * PIXSTRIDE + l * 2) = f2bf(v);
        }
        __syncthreads();

        const unsigned short* wq = wqBase + q * 3072;

        // ---- software-pipelined tap loop: prefetch A(tt+1) before MFMA(tt)
        v8s cA0, cA1, cA2, nA0, nA1, nA2;
        {
            const unsigned short* wp = wq + TBASE * 15360;
            cA0 = *(const v8s*)(wp);
            cA1 = *(const v8s*)(wp + 512);
            cA2 = *(const v8s*)(wp + 1024);
        }
        #pragma unroll
        for (int tt = 0; tt < NT; ++tt) {
            const int kh = tt / KSZ, kw = tt - kh * KSZ;

            // prefetch next tap's A-frags (no deps on current MFMAs)
            if (tt + 1 < NT) {
                const unsigned short* wp = wq + (TBASE + tt + 1) * 15360;
                nA0 = *(const v8s*)(wp);
                nA1 = *(const v8s*)(wp + 512);
                nA2 = *(const v8s*)(wp + 1024);
            }

            // B fragments for current tap
            const int rb0 = (ptb + kh) * PXR;
            v8s Bv[4];
            #pragma unroll
            for (int pp = 0; pp < 4; ++pp)
                Bv[pp] = *(const v8s*)(patchB + (rb0 + pp * PXR + kw) * PIXSTRIDE + laneBoff);

            #pragma unroll
            for (int pp = 0; pp < 4; ++pp) {
                acc[0][pp] = __builtin_amdgcn_mfma_f32_16x16x32_bf16(cA0, Bv[pp], acc[0][pp], 0, 0, 0);
                acc[1][pp] = __builtin_amdgcn_mfma_f32_16x16x32_bf16(cA1, Bv[pp], acc[1][pp], 0, 0, 0);
                acc[2][pp] = __builtin_amdgcn_mfma_f32_16x16x32_bf16(cA2, Bv[pp], acc[2][pp], 0, 0, 0);
            }

            // static rotation (unrolled loop -> pure register rename)
            cA0 = nA0; cA1 = nA1; cA2 = nA2;
        }
    }

    // ---- epilogue ----
    #pragma unroll
    for (int dt = 0; dt < 3; ++dt) {
        #pragma unroll
        for (int reg = 0; reg < 4; ++reg) {
            const int d = dhalf * 48 + dt * 16 + hi * 4 + reg;
            const float iv = bns[d*2+0], cv = bns[d*2+1];
            unsigned short* pl = (unsigned short*)(outp + (((size_t)b * D_ + d) << 12));
            #pragma unroll
            for (int pp = 0; pp < 4; ++pp) {
                const float y = fmaxf(0.f, fmaf(acc[dt][pp][reg], iv, cv));
                const int idx = ((h0 + ptb + pp) << 6) + w0 + lo;
                if constexpr (MODE == 0) {
                    pl[4096 + idx] = f2bf(y);
                } else if constexpr (MODE == 1) {
                    pl[idx] = f2bf(y);
                } else {
                    const float y2 = bf2f(pl[idx]);
                    const float y3 = bf2f(pl[4096 + idx]);
                    const float av = y + y2 + y3;
                    const float mv = fmaxf(y, fmaxf(y2, y3));
                    pl[idx]        = f2bf(av);
                    pl[4096 + idx] = f2bf(mv);
                }
            }
        }
    }
}

// ---------------------------------------------------------------------------
// Kernel B: per-plane 3x3 conv over [add; max] with avg folded (unchanged).
// ---------------------------------------------------------------------------
__global__ __launch_bounds__(256) void fuse_kernel(
    const float* __restrict__ wf, float* __restrict__ out)
{
    const int p = blockIdx.x;      // plane = b*96 + d
    const int t = threadIdx.x;
    __shared__ float sa[66 * 66];
    __shared__ float sm[66 * 66];
    const bf16* base = (const bf16*)(out + ((size_t)p << 12));

    for (int i = t; i < 66 * 66; i += 256) {
        const int c = i % 66, r = i / 66;
        const int gh = r - 1, gw = c - 1;
        float va = 0.f, vm = 0.f;
        if (gh >= 0 && gh < 64 && gw >= 0 && gw < 64) {
            va = __bfloat162float(base[(gh << 6) + gw]);
            vm = __bfloat162float(base[4096 + (gh << 6) + gw]);
        }
        sa[i] = va; sm[i] = vm;
    }

    float wa[9], wm[9];
    #pragma unroll
    for (int j = 0; j < 9; ++j) {
        wa[j] = wf[j] + wf[9 + j] * (1.f / 3.f);
        wm[j] = wf[18 + j];
    }
    __syncthreads();

    float* op = out + ((size_t)p << 12);
    for (int i = t; i < 4096; i += 256) {
        const int h = i >> 6, w = i & 63;
        float acc = 0.f;
        #pragma unroll
        for (int kh = 0; kh < 3; ++kh) {
            #pragma unroll
            for (int kw = 0; kw < 3; ++kw) {
                acc = fmaf(sa[(h + kh) * 66 + (w + kw)], wa[kh * 3 + kw], acc);
                acc = fmaf(sm[(h + kh) * 66 + (w + kw)], wm[kh * 3 + kw], acc);
            }
        }
        op[i] = acc;
    }
}

extern "C" void kernel_launch(void* const* d_in, const int* in_sizes, int n_in,
                              void* d_out, int out_size, void* d_ws, size_t ws_size,
                              hipStream_t stream)
{
    const float* x   = (const float*)d_in[0];
    const float* w1  = (const float*)d_in[1];
    const float* b1  = (const float*)d_in[2];
    const float* g1  = (const float*)d_in[3];
    const float* be1 = (const float*)d_in[4];
    const float* m1  = (const float*)d_in[5];
    const float* v1  = (const float*)d_in[6];
    const float* w2  = (const float*)d_in[7];
    const float* b2  = (const float*)d_in[8];
    const float* g2  = (const float*)d_in[9];
    const float* be2 = (const float*)d_in[10];
    const float* m2  = (const float*)d_in[11];
    const float* v2  = (const float*)d_in[12];
    const float* w3  = (const float*)d_in[13];
    const float* b3  = (const float*)d_in[14];
    const float* g3  = (const float*)d_in[15];
    const float* be3 = (const float*)d_in[16];
    const float* m3  = (const float*)d_in[17];
    const float* v3  = (const float*)d_in[18];
    const float* wf  = (const float*)d_in[19];
    float* out = (float*)d_out;

    // d_ws: packed bf16 weights only (2.55 MB, proven safe rounds 4-9)
    unsigned short* wpack = (unsigned short*)d_ws;

    prep_weights<<<(WPACK_ELEMS + 255) / 256, 256, 0, stream>>>(w1, w2, w3, wpack);

    dim3 gridA(16, B_);   // 16 spatial tiles x 32 batch
    conv_branch<7, 0, 0><<<gridA, 512, 0, stream>>>(x, wpack, b3, g3, be3, m3, v3, out);
    conv_branch<5, 49, 1><<<gridA, 512, 0, stream>>>(x, wpack, b2, g2, be2, m2, v2, out);
    conv_branch<3, 74, 2><<<gridA, 512, 0, stream>>>(x, wpack, b1, g1, be1, m1, v1, out);

    fuse_kernel<<<B_ * D_, 256, 0, stream>>>(wf, out);
}

// Round 11
// 608.698 us; speedup vs baseline: 1.6583x; 1.1137x over previous
//
#include <hip/hip_runtime.h>
#include <hip/hip_bf16.h>

typedef __hip_bfloat16 bf16;
typedef short v8s __attribute__((ext_vector_type(8)));     // 8 bf16 (4 VGPRs)
typedef float f32x4 __attribute__((ext_vector_type(4)));   // MFMA acc

#define B_  32
#define L_  144
#define D_  96
#define HW_ 64

#define WPACK_ELEMS (83*5*96*32) // packed bf16 weights

__device__ __forceinline__ unsigned short f2bf(float f) {
    union { float f; unsigned int u; } x{f};
    unsigned int r = x.u + 0x7fffu + ((x.u >> 16) & 1u);   // RNE
    return (unsigned short)(r >> 16);
}
__device__ __forceinline__ float bf2f(unsigned short u) {
    union { unsigned int u; float f; } x{(unsigned int)u << 16};
    return x.f;
}

// ---------------------------------------------------------------------------
// Weight prep: pack w1/w2/w3 (fp32, [D][L][k][k]) into A-fragment order bf16:
// wpack[((T*5+q)*96 + d)*32 + l~],  T: 0..48=7x7 taps, 49..73=5x5, 74..82=3x3,
// q = l-chunk (l = q*32+l~, zero-padded past 143).
// ---------------------------------------------------------------------------
__global__ __launch_bounds__(256) void prep_weights(
    const float* __restrict__ w1, const float* __restrict__ w2,
    const float* __restrict__ w3, unsigned short* __restrict__ wpack)
{
    int i = blockIdx.x * 256 + threadIdx.x;
    if (i >= WPACK_ELEMS) return;
    const int lt = i & 31;
    const int d  = (i >> 5) % 96;
    const int r  = (i >> 5) / 96;   // T*5 + q
    const int q  = r % 5;
    const int T  = r / 5;
    const int l  = q * 32 + lt;
    float v = 0.f;
    if (l < L_) {
        if (T < 49)      v = w3[(d * L_ + l) * 49 + T];
        else if (T < 74) v = w2[(d * L_ + l) * 25 + (T - 49)];
        else             v = w1[(d * L_ + l) * 9  + (T - 74)];
    }
    wpack[i] = f2bf(v);
}

// ---------------------------------------------------------------------------
// Single-branch MFMA conv (round-7 register structure, UNchanged: 12 accs,
// VGPR ~52-80, 4 waves/SIMD) with a conflict-free TRANSPOSED LDS layout:
//   patchB[hi][pixel][16B],  pixel dim padded to PADN = NPIX+2
// B-read addr = base + hi*PADN*16 + pixel*16 -> 16B columns; lane (lo,hi)
// hits column (lo + 6*hi) & 7: 64 lanes = exactly 8 per column, 0 conflicts
// (round 7: 1.98e7 conflict cycles at 80B pixel stride). All tap offsets are
// ds_read immediates. Staging: thread owns one pixel (div/mod hoisted out of
// the q loop), 32 strided f32 loads -> 4 ds_write_b128.
// MODE 0: y -> slot upper half (7x7/y3); MODE 1: y -> lower (5x5/y2);
// MODE 2: y1 + combine: add -> lower, max -> upper.
// ---------------------------------------------------------------------------
template<int KSZ, int TBASE, int MODE>
__global__ __launch_bounds__(512, 4) void conv_branch(
    const float* __restrict__ x, const unsigned short* __restrict__ wpack,
    const float* __restrict__ bb, const float* __restrict__ gg,
    const float* __restrict__ bbe, const float* __restrict__ mm,
    const float* __restrict__ vv,
    float* __restrict__ outp)
{
    constexpr int PAD  = KSZ / 2;
    constexpr int PXR  = 16 + 2 * PAD;    // patch rows/cols
    constexpr int NPIX = PXR * PXR;
    constexpr int PADN = NPIX + 2;        // NPIX%8==0|4 -> PADN%8 in {2,6}: hi-offsets distinct mod 32

    __shared__ __align__(16) unsigned char patchB[4 * PADN * 16];
    __shared__ float bns[96 * 2];

    const int t    = threadIdx.x;
    const int lane = t & 63;
    const int wid  = t >> 6;           // 0..7
    const int dhalf = wid >> 2;        // 0..1
    const int ptb   = (wid & 3) * 4;   // px-quad base row
    const int lo = lane & 15;
    const int hi = lane >> 4;

    const int st = blockIdx.x;
    const int h0 = (st >> 2) << 4;
    const int w0 = (st & 3) << 4;
    const int b  = blockIdx.y;

    // ---- staging precompute (once; q loop only varies the channel) ----
    const bool pvalid = (t < NPIX);
    const int pr = t / PXR, pc = t - pr * PXR;          // this thread's pixel
    const int gh = h0 - PAD + pr, gw = w0 - PAD + pc;
    const bool inb = pvalid && ((unsigned)gh < 64u) && ((unsigned)gw < 64u);
    const float* xpix = x + (((size_t)b * L_) << 12) + (gh << 6) + gw;

    if (t < 96) {
        const float iv = gg[t] * rsqrtf(vv[t] + 1e-5f);
        bns[t*2+0] = iv;
        bns[t*2+1] = fmaf(bb[t] - mm[t], iv, bbe[t]);
    }

    f32x4 acc[3][4];
    #pragma unroll
    for (int dt = 0; dt < 3; ++dt)
        #pragma unroll
        for (int pp = 0; pp < 4; ++pp) acc[dt][pp] = (f32x4)0.f;

    const unsigned short* wqBase = wpack + dhalf * 1536 + lo * 32 + hi * 8;
    // thread-constant B base; all tap/pp offsets are compile-time immediates
    unsigned char* pB = patchB + (hi * PADN + ptb * PXR + lo) * 16;

    for (int q = 0; q < 5; ++q) {
        __syncthreads();
        // ---- stage chunk q: thread's pixel, channels q*32..q*32+31 ----
        if (pvalid) {
            #pragma unroll
            for (int s = 0; s < 4; ++s) {          // hi-section s: channels s*8..s*8+7
                v8s v;
                #pragma unroll
                for (int j = 0; j < 8; ++j) {
                    const int lg = q * 32 + s * 8 + j;
                    float f = 0.f;
                    if (inb && lg < L_) f = xpix[(size_t)lg << 12];
                    ((unsigned short*)&v)[j] = f2bf(f);
                }
                *(v8s*)(patchB + (s * PADN + t) * 16) = v;
            }
        }
        __syncthreads();

        const unsigned short* wq = wqBase + q * 3072;

        for (int kh = 0; kh < KSZ; ++kh) {
            #pragma unroll
            for (int kw = 0; kw < KSZ; ++kw) {
                const unsigned short* wp = wq + (TBASE + kh * KSZ + kw) * 15360;
                const v8s A0 = *(const v8s*)(wp);
                const v8s A1 = *(const v8s*)(wp + 512);
                const v8s A2 = *(const v8s*)(wp + 1024);
                v8s Bv[4];
                #pragma unroll
                for (int pp = 0; pp < 4; ++pp)
                    Bv[pp] = *(const v8s*)(pB + ((pp + kh) * PXR + kw) * 16);
                #pragma unroll
                for (int pp = 0; pp < 4; ++pp) {
                    acc[0][pp] = __builtin_amdgcn_mfma_f32_16x16x32_bf16(A0, Bv[pp], acc[0][pp], 0, 0, 0);
                    acc[1][pp] = __builtin_amdgcn_mfma_f32_16x16x32_bf16(A1, Bv[pp], acc[1][pp], 0, 0, 0);
                    acc[2][pp] = __builtin_amdgcn_mfma_f32_16x16x32_bf16(A2, Bv[pp], acc[2][pp], 0, 0, 0);
                }
            }
        }
    }

    // ---- epilogue ----
    #pragma unroll
    for (int dt = 0; dt < 3; ++dt) {
        #pragma unroll
        for (int reg = 0; reg < 4; ++reg) {
            const int d = dhalf * 48 + dt * 16 + hi * 4 + reg;
            const float iv = bns[d*2+0], cv = bns[d*2+1];
            unsigned short* pl = (unsigned short*)(outp + (((size_t)b * D_ + d) << 12));
            #pragma unroll
            for (int pp = 0; pp < 4; ++pp) {
                const float y = fmaxf(0.f, fmaf(acc[dt][pp][reg], iv, cv));
                const int idx = ((h0 + ptb + pp) << 6) + w0 + lo;
                if constexpr (MODE == 0) {
                    pl[4096 + idx] = f2bf(y);
                } else if constexpr (MODE == 1) {
                    pl[idx] = f2bf(y);
                } else {
                    const float y2 = bf2f(pl[idx]);
                    const float y3 = bf2f(pl[4096 + idx]);
                    const float av = y + y2 + y3;
                    const float mv = fmaxf(y, fmaxf(y2, y3));
                    pl[idx]        = f2bf(av);
                    pl[4096 + idx] = f2bf(mv);
                }
            }
        }
    }
}

// ---------------------------------------------------------------------------
// Kernel B: per-plane 3x3 conv over [add; max] with avg folded (unchanged).
// ---------------------------------------------------------------------------
__global__ __launch_bounds__(256) void fuse_kernel(
    const float* __restrict__ wf, float* __restrict__ out)
{
    const int p = blockIdx.x;      // plane = b*96 + d
    const int t = threadIdx.x;
    __shared__ float sa[66 * 66];
    __shared__ float sm[66 * 66];
    const bf16* base = (const bf16*)(out + ((size_t)p << 12));

    for (int i = t; i < 66 * 66; i += 256) {
        const int c = i % 66, r = i / 66;
        const int gh = r - 1, gw = c - 1;
        float va = 0.f, vm = 0.f;
        if (gh >= 0 && gh < 64 && gw >= 0 && gw < 64) {
            va = __bfloat162float(base[(gh << 6) + gw]);
            vm = __bfloat162float(base[4096 + (gh << 6) + gw]);
        }
        sa[i] = va; sm[i] = vm;
    }

    float wa[9], wm[9];
    #pragma unroll
    for (int j = 0; j < 9; ++j) {
        wa[j] = wf[j] + wf[9 + j] * (1.f / 3.f);
        wm[j] = wf[18 + j];
    }
    __syncthreads();

    float* op = out + ((size_t)p << 12);
    for (int i = t; i < 4096; i += 256) {
        const int h = i >> 6, w = i & 63;
        float acc = 0.f;
        #pragma unroll
        for (int kh = 0; kh < 3; ++kh) {
            #pragma unroll
            for (int kw = 0; kw < 3; ++kw) {
                acc = fmaf(sa[(h + kh) * 66 + (w + kw)], wa[kh * 3 + kw], acc);
                acc = fmaf(sm[(h + kh) * 66 + (w + kw)], wm[kh * 3 + kw], acc);
            }
        }
        op[i] = acc;
    }
}

extern "C" void kernel_launch(void* const* d_in, const int* in_sizes, int n_in,
                              void* d_out, int out_size, void* d_ws, size_t ws_size,
                              hipStream_t stream)
{
    const float* x   = (const float*)d_in[0];
    const float* w1  = (const float*)d_in[1];
    const float* b1  = (const float*)d_in[2];
    const float* g1  = (const float*)d_in[3];
    const float* be1 = (const float*)d_in[4];
    const float* m1  = (const float*)d_in[5];
    const float* v1  = (const float*)d_in[6];
    const float* w2  = (const float*)d_in[7];
    const float* b2  = (const float*)d_in[8];
    const float* g2  = (const float*)d_in[9];
    const float* be2 = (const float*)d_in[10];
    const float* m2  = (const float*)d_in[11];
    const float* v2  = (const float*)d_in[12];
    const float* w3  = (const float*)d_in[13];
    const float* b3  = (const float*)d_in[14];
    const float* g3  = (const float*)d_in[15];
    const float* be3 = (const float*)d_in[16];
    const float* m3  = (const float*)d_in[17];
    const float* v3  = (const float*)d_in[18];
    const float* wf  = (const float*)d_in[19];
    float* out = (float*)d_out;

    // d_ws: packed bf16 weights only (2.55 MB, proven safe rounds 4-10)
    unsigned short* wpack = (unsigned short*)d_ws;

    prep_weights<<<(WPACK_ELEMS + 255) / 256, 256, 0, stream>>>(w1, w2, w3, wpack);

    dim3 gridA(16, B_);   // 16 spatial tiles x 32 batch
    conv_branch<7, 0, 0><<<gridA, 512, 0, stream>>>(x, wpack, b3, g3, be3, m3, v3, out);
    conv_branch<5, 49, 1><<<gridA, 512, 0, stream>>>(x, wpack, b2, g2, be2, m2, v2, out);
    conv_branch<3, 74, 2><<<gridA, 512, 0, stream>>>(x, wpack, b1, g1, be1, m1, v1, out);

    fuse_kernel<<<B_ * D_, 256, 0, stream>>>(wf, out);
}